// Round 11
// baseline (48.746 us; speedup 1.0000x reference)
//
#include <hip/hip_runtime.h>

// KAConv: out[b,f,h,w] = sum_{c,p} P_fcp(v) / (1 + |Q_fcp(v)|),
//   v = x[b,c,h+i-1,w+j-1] (zero pad), p = i*3+j
// Shapes: x[4,16,64,64], A[16,16,9,6], Bc[16,16,9,4], out[4,16,64,64], f32.
//
// Round 11: lane = (f, pixel-slot) — coefficients become PER-LANE VECTOR
// data (coalesced global_load_dwordx2/x4, L1-hot, vmcnt-pipelined), killing
// the scalar-pipe coefficient stream that every lane=pixel round (r1-r10)
// either stalled on (s_load bursts) or paid VALU/LDS overhead to avoid.
// Windows (f-independent) are the broadcast quantity: staged once per block
// in LDS, read via aligned ds_read_b128/b64 into registers per (c,ri),
// reused across 16 f x 8 px. Prep kernel repacks coeffs to [c][p][f][i].
// Zero redundant tap-evals: 4096 waves x 64 lanes x 144 = 37.7M exactly.

#define CIN  16
#define COUT 16
#define HH   64
#define WW   64

typedef float f2 __attribute__((ext_vector_type(2)));
typedef float f4 __attribute__((ext_vector_type(4)));

#define NA (CIN * 9 * COUT * 6)   // 13824 dwords, A' = [c][p][f][6]
#define NB (CIN * 9 * COUT * 4)   //  9216 dwords, B' = [c][p][f][4]

// ---------------- prep: repack coefficients --------------------------------
__global__ __launch_bounds__(256) void repack_kernel(
    const float* __restrict__ A,    // [f][c][p][6]
    const float* __restrict__ Bc,   // [f][c][p][4]
    float* __restrict__ ws)
{
    const int i = blockIdx.x * 256 + threadIdx.x;
    if (i < NA) {
        const int i6 = i % 6;  const int r  = i / 6;
        const int f  = r & 15; const int r2 = r >> 4;
        const int p  = r2 % 9; const int c  = r2 / 9;
        ws[i] = A[((f * 16 + c) * 9 + p) * 6 + i6];
    } else if (i < NA + NB) {
        const int j  = i - NA;
        const int i4 = j & 3;  const int r  = j >> 2;
        const int f  = r & 15; const int r2 = r >> 4;
        const int p  = r2 % 9; const int c  = r2 / 9;
        ws[i] = Bc[((f * 16 + c) * 9 + p) * 4 + i4];
    }
}

// ---------------- main -----------------------------------------------------
__global__ __launch_bounds__(512, 4) void KAConv_kernel(
    const float* __restrict__ x,    // [B,C,H,W]
    const float* __restrict__ cw,   // repacked coeffs
    float* __restrict__ out)        // [B,F,H,W]
{
    // grid = b(4) x row(64) x colhalf(2) = 512 blocks; block = 512 = 8 waves.
    const int blk  = blockIdx.x;
    const int half = blk & 1;
    const int row  = (blk >> 1) & 63;
    const int b    = blk >> 7;
    const int cb   = half << 5;          // 32-col base

    const int tid  = threadIdx.x;
    const int team = tid >> 6;           // wave id 0..7 -> channels 2t, 2t+1
    const int lane = tid & 63;
    const int f    = lane & 15;          // output channel (per-lane!)
    const int slot = lane >> 4;          // 0..3 -> pixels slot*8 .. slot*8+7

    const float* __restrict__ cA = cw;         // [c][p][f][6]
    const float* __restrict__ cB = cw + NA;    // [c][p][f][4]

    __shared__ float winS[CIN][3][36];         // 6.75 KB (36: 16B-mult stride)
    __shared__ float sRed[8][COUT][33];        // 16.5 KB (33: bank-spread pad)

    // ---- Stage windows: 16 c x 3 rows x 34 cols, zero-padded ----
    for (int i = tid; i < CIN * 3 * 36; i += 512) {
        const int c   = i / 108;
        const int rem = i - c * 108;
        const int ri  = rem / 36;
        const int tc  = rem - ri * 36;
        const int gh  = row - 1 + ri;
        const int gw  = cb - 1 + tc;
        const bool ok = (tc < 34) & (gh >= 0) & (gh < HH) & (gw >= 0) & (gw < WW);
        winS[c][ri][tc] = ok ? x[((b * CIN + c) * HH + gh) * WW + gw] : 0.0f;
    }
    __syncthreads();

    float acc[8];
    #pragma unroll
    for (int q = 0; q < 8; ++q) acc[q] = 0.0f;

    const int fA = f * 6;                // per-lane dword offsets
    const int fB = f * 4;

    #pragma unroll
    for (int c2 = 0; c2 < 2; ++c2) {
        const int c = team * 2 + c2;     // wave-uniform

        // Window registers: 3 rows x 10 cols (slot's 8 px + 2 halo), via
        // aligned b128/b128/b64 broadcast reads (slot groups: disjoint banks).
        float wr[3][10];
        #pragma unroll
        for (int ri = 0; ri < 3; ++ri) {
            const float* wsrc = &winS[c][ri][slot * 8];
            const f4 w0 = *(const f4*)(wsrc);
            const f4 w1 = *(const f4*)(wsrc + 4);
            const f2 w2 = *(const f2*)(wsrc + 8);
            wr[ri][0] = w0.x; wr[ri][1] = w0.y; wr[ri][2] = w0.z; wr[ri][3] = w0.w;
            wr[ri][4] = w1.x; wr[ri][5] = w1.y; wr[ri][6] = w1.z; wr[ri][7] = w1.w;
            wr[ri][8] = w2.x; wr[ri][9] = w2.y;
        }

        #pragma unroll
        for (int p = 0; p < 9; ++p) {
            const int ri = p / 3, j = p % 3;   // compile-time
            const float* pA = cA + (c * 9 + p) * 96 + fA;
            const float* pB = cB + (c * 9 + p) * 64 + fB;
            const f2 a01 = *(const f2*)(pA);       // coalesced vector loads,
            const f2 a23 = *(const f2*)(pA + 2);   // per-lane f -> no scalar
            const f2 a45 = *(const f2*)(pA + 4);   // pipe traffic at all
            const f4 b14 = *(const f4*)(pB);

            #pragma unroll
            for (int qi = 0; qi < 8; ++qi) {       // 8 independent chains
                const float v = wr[ri][qi + j];    // compile-time index
                float P = a45.y;
                P = fmaf(P, v, a45.x); P = fmaf(P, v, a23.y);
                P = fmaf(P, v, a23.x); P = fmaf(P, v, a01.y);
                P = fmaf(P, v, a01.x);
                float q = b14.w;
                q = fmaf(q, v, b14.z); q = fmaf(q, v, b14.y);
                q = fmaf(q, v, b14.x);
                q *= v;
                const float d = 1.0f + fabsf(q);
                acc[qi] = fmaf(P, __builtin_amdgcn_rcpf(d), acc[qi]);
            }
        }
    }

    // ---- Cross-team (channel) reduction ----
    #pragma unroll
    for (int qi = 0; qi < 8; ++qi)
        sRed[team][f][slot * 8 + qi] = acc[qi];    // <=2-way banks (pad 33)
    __syncthreads();

    {
        const int fo = tid >> 5;         // 0..15
        const int px = tid & 31;
        float s = 0.0f;
        #pragma unroll
        for (int k = 0; k < 8; ++k) s += sRed[k][fo][px];
        out[((b * COUT + fo) * HH + row) * WW + cb + px] = s;   // coalesced
    }
}

extern "C" void kernel_launch(void* const* d_in, const int* in_sizes, int n_in,
                              void* d_out, int out_size, void* d_ws, size_t ws_size,
                              hipStream_t stream) {
    const float* x  = (const float*)d_in[0];
    const float* A  = (const float*)d_in[1];
    const float* Bc = (const float*)d_in[2];
    float* out = (float*)d_out;
    float* cw  = (float*)d_ws;           // 92.2 KB scratch

    const int nrep = NA + NB;            // 23040
    repack_kernel<<<(nrep + 255) / 256, 256, 0, stream>>>(A, Bc, cw);

    const int grid = 4 * HH * 2;         // 512 blocks
    KAConv_kernel<<<grid, 512, 0, stream>>>(x, cw, out);
}

// Round 12
// 20.098 us; speedup vs baseline: 2.4254x; 2.4254x over previous
//
#include <hip/hip_runtime.h>

// KAConv: out[b,f,h,w] = sum_{c,p} P_fcp(v) / (1 + |Q_fcp(v)|),
//   v = x[b,c,h+i-1,w+j-1] (zero pad), p = i*3+j
// Shapes: x[4,16,64,64], A[16,16,9,6], Bc[16,16,9,4], out[4,16,64,64], f32.
//
// Round 12: TAP-OUTER loop order. Every prior round was tap-inner, keeping a
// 90-dword scalar working set live (=> SGPR-chunked s_load stalls (r1-r5,r10)
// or one-shot SGPR-resident waves (r8, 650-cyc lifetime, phase-correlated
// vmcnt stalls)). Now: per tap p (9, unrolled) load 10 coeff dwords (one tiny
// s_load group) and apply to 8 output rows (8x register reuse). Wave =
// channel, lane = column, 8 rows/block: per-wave compute ~2200 busy cycles
// against ONE exposed load-latency window (30 window loads issued upfront,
// counted-vmcnt overlap). 2 blocks/CU, one barrier, conflict-free reduce.

#define BB   4
#define CIN  16
#define COUT 16
#define HH   64
#define WW   64

__global__ __launch_bounds__(1024, 8) void KAConv_kernel(
    const float* __restrict__ x,    // [B,C,H,W]
    const float* __restrict__ A,    // [F,C,9,6]
    const float* __restrict__ Bc,   // [F,C,9,4]
    float* __restrict__ out)        // [B,F,H,W]
{
    // grid = b(4) x f(16) x rowgroup(8) = 512 blocks; block = 1024 = 16 waves.
    const int blk = blockIdx.x;
    const int rg  = blk & 7;
    const int f   = (blk >> 3) & 15;
    const int b   = blk >> 7;

    const int tid   = threadIdx.x;
    const int c     = __builtin_amdgcn_readfirstlane(tid >> 6);  // wave = channel
    const int w     = tid & 63;                                  // lane = column
    const int rbase = rg << 3;                                   // 8 output rows

    const float* __restrict__ xc = x  + (b * CIN + c) * (HH * WW);
    const float* __restrict__ Ac = A  + (f * CIN + c) * 54;
    const float* __restrict__ Bq = Bc + (f * CIN + c) * 36;

    // ---- 30 window loads upfront: rows rbase-1 .. rbase+8, cols w-1..w+1.
    // Counted vmcnt lets tap-0 compute start once its rows land.
    float win[10][3];
    #pragma unroll
    for (int rr = 0; rr < 10; ++rr) {
        const int hh   = rbase - 1 + rr;
        const bool okh = (hh >= 0) & (hh < HH);
        #pragma unroll
        for (int j = 0; j < 3; ++j) {
            const int wj  = w - 1 + j;
            const bool ok = okh & (wj >= 0) & (wj < WW);
            win[rr][j] = ok ? xc[hh * WW + wj] : 0.0f;
        }
    }

    float acc[8];
    #pragma unroll
    for (int r = 0; r < 8; ++r) acc[r] = 0.0f;

    // ---- Tap-outer: 10 scalar dwords live at a time, reused across 8 rows.
    #pragma unroll
    for (int p = 0; p < 9; ++p) {
        const int pi = p / 3, pj = p % 3;     // compile-time
        const float a0 = Ac[p*6+0], a1 = Ac[p*6+1], a2 = Ac[p*6+2];
        const float a3 = Ac[p*6+3], a4 = Ac[p*6+4], a5 = Ac[p*6+5];
        const float b1 = Bq[p*4+0], b2 = Bq[p*4+1];
        const float b3 = Bq[p*4+2], b4 = Bq[p*4+3];

        #pragma unroll
        for (int r = 0; r < 8; ++r) {         // 8 independent chains
            const float v = win[r + pi][pj];  // compile-time index
            float P = a5;
            P = fmaf(P, v, a4); P = fmaf(P, v, a3); P = fmaf(P, v, a2);
            P = fmaf(P, v, a1); P = fmaf(P, v, a0);
            float q = b4;
            q = fmaf(q, v, b3); q = fmaf(q, v, b2); q = fmaf(q, v, b1);
            q *= v;
            const float d = 1.0f + fabsf(q);
            acc[r] = fmaf(P, __builtin_amdgcn_rcpf(d), acc[r]);
        }
    }

    // ---- One barrier; conflict-free channel reduction ----
    __shared__ float sRed[CIN][8][66];        // 33 KB, 66: bank-spread pad
    #pragma unroll
    for (int r = 0; r < 8; ++r)
        sRed[c][r][w] = acc[r];               // lanes stride-1: conflict-free
    __syncthreads();

    if (tid < 512) {
        const int row = tid >> 6;             // 0..7
        const int px  = tid & 63;
        float s = 0.0f;
        #pragma unroll
        for (int k = 0; k < CIN; ++k) s += sRed[k][row][px];  // stride-1/instr
        out[((b * COUT + f) * HH + rbase + row) * WW + px] = s;  // coalesced
    }
}

extern "C" void kernel_launch(void* const* d_in, const int* in_sizes, int n_in,
                              void* d_out, int out_size, void* d_ws, size_t ws_size,
                              hipStream_t stream) {
    const float* x  = (const float*)d_in[0];
    const float* A  = (const float*)d_in[1];
    const float* Bc = (const float*)d_in[2];
    float* out = (float*)d_out;

    const int grid = BB * COUT * (HH / 8);   // 512 blocks, 2 per CU
    KAConv_kernel<<<grid, 1024, 0, stream>>>(x, A, Bc, out);
}